// Round 3
// baseline (3026.789 us; speedup 1.0000x reference)
//
#include <hip/hip_runtime.h>

// ---------------------------------------------------------------------------
// CrossAttention_83528523972835 — round 3: fix eps PRNG. JAX ≥0.4.36 defaults
// jax_threefry_partitionable=True → random_bits is counter-based: for flat
// index i (< 2^32): threefry2x32(key, c0=0, c1=i), bits = out0 ^ out1.
// (Round 2 used the legacy split-halves construction → decorrelated eps →
// head absmax 0.25, matching the predicted fingerprint of wrong-eps.)
// Everything else unchanged from round 2.
// ---------------------------------------------------------------------------

typedef unsigned short u16;
typedef short bf16x8 __attribute__((ext_vector_type(8)));
typedef unsigned short u16x8 __attribute__((ext_vector_type(8)));
typedef float f32x4 __attribute__((ext_vector_type(4)));

static __device__ __forceinline__ u16 f2b(float f) {
    union { float f; unsigned int u; } cv; cv.f = f;
    unsigned int u = cv.u;
    unsigned int lsb = (u >> 16) & 1u;
    u += 0x7fffu + lsb;
    return (u16)(u >> 16);
}

// ---------------------------------------------------------------------------
// Generic bf16 GEMM: C[M,N] = alpha * A[M,K] @ Bt[N,K]^T + bias
// row_remap: C row r -> (r>>6)*129 + 65 + (r&63)
// batching: blockIdx.z = bz; A += bz*sA, Bt += bz*sB,
//           C += (bz/binner)*sCo + (bz%binner)*sCi
// ---------------------------------------------------------------------------
__global__ __launch_bounds__(256) void gemm_bt(
    const u16* __restrict__ A, const u16* __restrict__ Bt, void* __restrict__ Cv,
    const float* __restrict__ bias, int M, int N, int K,
    int lda, int ldb, int ldc, float alpha, int c_bf16, int row_remap,
    long sA, long sB, long sCo, long sCi, int binner)
{
    const int bz = blockIdx.z;
    const u16* Ab = A + (long)bz * sA;
    const u16* Bb = Bt + (long)bz * sB;
    const long cOff = (long)(bz / binner) * sCo + (long)(bz % binner) * sCi;

    __shared__ u16 As[128][72];
    __shared__ u16 Bs[128][72];

    const int tid = threadIdx.x;
    const int lane = tid & 63;
    const int wave = tid >> 6;
    const int wr = wave >> 1, wc = wave & 1;     // 2x2 waves, 64x64 quadrants
    const int l15 = lane & 15, l4 = lane >> 4;
    const int m0 = blockIdx.x * 128, n0 = blockIdx.y * 128;

    const int r = tid >> 3;           // 0..31 staging row
    const int kof = (tid & 7) * 8;    // 0..56 staging k offset

    f32x4 acc[4][4] = {};

    const int ktiles = (K + 63) / 64;
    for (int kt = 0; kt < ktiles; ++kt) {
        const int k0 = kt * 64;
        __syncthreads();
        #pragma unroll
        for (int i = 0; i < 4; ++i) {
            const int row = r + 32 * i;
            const int gk = k0 + kof;
            u16x8 v = {0,0,0,0,0,0,0,0};
            const int grow = m0 + row;
            if (grow < M && gk < K)
                v = *(const u16x8*)(Ab + (long)grow * lda + gk);
            *(u16x8*)&As[row][kof] = v;
        }
        #pragma unroll
        for (int i = 0; i < 4; ++i) {
            const int row = r + 32 * i;
            const int gk = k0 + kof;
            u16x8 v = {0,0,0,0,0,0,0,0};
            const int gcol = n0 + row;
            if (gcol < N && gk < K)
                v = *(const u16x8*)(Bb + (long)gcol * ldb + gk);
            *(u16x8*)&Bs[row][kof] = v;
        }
        __syncthreads();
        #pragma unroll
        for (int ks = 0; ks < 2; ++ks) {
            bf16x8 af[4], bfr[4];
            #pragma unroll
            for (int m = 0; m < 4; ++m)
                af[m] = *(const bf16x8*)&As[wr*64 + m*16 + l15][ks*32 + l4*8];
            #pragma unroll
            for (int n = 0; n < 4; ++n)
                bfr[n] = *(const bf16x8*)&Bs[wc*64 + n*16 + l15][ks*32 + l4*8];
            #pragma unroll
            for (int m = 0; m < 4; ++m)
                #pragma unroll
                for (int n = 0; n < 4; ++n)
                    acc[m][n] = __builtin_amdgcn_mfma_f32_16x16x32_bf16(
                        af[m], bfr[n], acc[m][n], 0, 0, 0);
        }
    }

    // D mapping: col = lane&15, row = 4*(lane>>4) + reg   [m89-verified]
    #pragma unroll
    for (int m = 0; m < 4; ++m) {
        #pragma unroll
        for (int n = 0; n < 4; ++n) {
            const int col = n0 + wc*64 + n*16 + l15;
            if (col >= N) continue;
            const float bv = bias ? bias[col] : 0.0f;
            #pragma unroll
            for (int j = 0; j < 4; ++j) {
                const int row = m0 + wr*64 + m*16 + l4*4 + j;
                if (row >= M) continue;
                float v = alpha * acc[m][n][j] + bv;
                long crow = row;
                if (row_remap) crow = (long)(row >> 6) * 129 + 65 + (row & 63);
                if (c_bf16) ((u16*)Cv)[cOff + crow * (long)ldc + col] = f2b(v);
                else        ((float*)Cv)[cOff + crow * (long)ldc + col] = v;
            }
        }
    }
}

// out[n][k] = (n<N && k<K) ? in[k][n] : 0 ; out is [NPd][KP] bf16
__global__ __launch_bounds__(256) void transpose_conv(
    const float* __restrict__ in, u16* __restrict__ out, int K, int N, int KP, int NPd)
{
    __shared__ float tile[32][33];
    const int k0 = blockIdx.x * 32, n0 = blockIdx.y * 32;
    const int tx = threadIdx.x, ty = threadIdx.y;   // (32,8)
    #pragma unroll
    for (int i = 0; i < 4; ++i) {
        const int k = k0 + ty + i*8, n = n0 + tx;
        tile[ty + i*8][tx] = (k < K && n < N) ? in[(long)k * N + n] : 0.0f;
    }
    __syncthreads();
    #pragma unroll
    for (int i = 0; i < 4; ++i) {
        const int n = n0 + ty + i*8, k = k0 + tx;
        if (n < NPd && k < KP) out[(long)n * KP + k] = f2b(tile[tx][ty + i*8]);
    }
}

// out[b*64 + hh*8+ww][(p1*7+p2)*128 + c] = x[b][c][hh*7+p1][ww*7+p2]
__global__ __launch_bounds__(256) void patchify_kernel(
    const float* __restrict__ x, u16* __restrict__ out)
{
    const int f = blockIdx.x * 256 + threadIdx.x;
    if (f >= 6272) return;
    const int row = blockIdx.y;
    const int b = row >> 6, patch = row & 63;
    const int hh = patch >> 3, ww = patch & 7;
    const int c = f & 127, pp = f >> 7;
    const int p1 = pp / 7, p2 = pp - p1 * 7;
    const float v = x[(((long)b * 128 + c) * 56 + hh*7 + p1) * 56 + ww*7 + p2];
    out[(long)row * 6272 + f] = f2b(v);
}

__global__ __launch_bounds__(256) void posfill_kernel(
    const float* __restrict__ pos, u16* __restrict__ Tq, u16* __restrict__ Tk)
{
    const int col = blockIdx.x * 256 + threadIdx.x;
    const int t = blockIdx.y, b = blockIdx.z;
    const u16 v = f2b(pos[(long)t * 2048 + col]);
    const long idx = ((long)b * 129 + t) * 2048 + col;
    Tq[idx] = v; Tk[idx] = v;
}

// v_t[bh][d][n (pad 144)] = vmat[(b*129+n)*2048 + h*256 + d]; pads zeroed
__global__ void vtrans_kernel(const u16* __restrict__ vmat, u16* __restrict__ v_t)
{
    const int bh = blockIdx.z; const int b = bh >> 3, h = bh & 7;
    const int d0 = blockIdx.x * 32, n0 = blockIdx.y * 32;
    __shared__ u16 tile[32][33];
    const int tx = threadIdx.x, ty = threadIdx.y;   // (32,8)
    #pragma unroll
    for (int i = 0; i < 4; ++i) {
        const int n = n0 + ty + i*8;
        if (n < 129)
            tile[ty + i*8][tx] = vmat[((long)b*129 + n) * 2048 + h*256 + d0 + tx];
    }
    __syncthreads();
    #pragma unroll
    for (int i = 0; i < 4; ++i) {
        const int d = d0 + ty + i*8, n = n0 + tx;
        if (n < 144)
            v_t[((long)bh * 256 + d) * 144 + n] = (n < 129) ? tile[tx][ty + i*8] : (u16)0;
    }
}

// --------------------- threefry2x32, partitionable path --------------------
// JAX (threefry_partitionable=True, default since 0.4.36): for flat index i,
// counter = uint64(i) → (c0, c1) = (hi32, lo32) = (0, i); run threefry2x32
// with key (0, 42); 32-bit output = out0 ^ out1.
static __device__ __forceinline__ unsigned int rotl32(unsigned int x, int d) {
    return (x << d) | (x >> (32 - d));
}

static __device__ __forceinline__ float threefry_normal(unsigned int i) {
    const unsigned int ks0 = 0u, ks1 = 42u;
    const unsigned int ks2 = ks0 ^ ks1 ^ 0x1BD11BDAu;
    unsigned int x0 = 0u + ks0;        // counts_hi = 0
    unsigned int x1 = i + ks1;         // counts_lo = i
#define TF_R(rr) { x0 += x1; x1 = rotl32(x1, rr); x1 ^= x0; }
    TF_R(13) TF_R(15) TF_R(26) TF_R(6)
    x0 += ks1; x1 += ks2 + 1u;
    TF_R(17) TF_R(29) TF_R(16) TF_R(24)
    x0 += ks2; x1 += ks0 + 2u;
    TF_R(13) TF_R(15) TF_R(26) TF_R(6)
    x0 += ks0; x1 += ks1 + 3u;
    TF_R(17) TF_R(29) TF_R(16) TF_R(24)
    x0 += ks1; x1 += ks2 + 4u;
    TF_R(13) TF_R(15) TF_R(26) TF_R(6)
    x0 += ks2; x1 += ks0 + 5u;
#undef TF_R
    const unsigned int bits = x0 ^ x1;            // partitionable 32-bit path
    const unsigned int fb = (bits >> 9) | 0x3f800000u;
    union { unsigned int u; float f; } cv; cv.u = fb;
    const float f = cv.f - 1.0f;                  // [0,1)
    const float lo = -0.99999994f;                // nextafter(-1,0)
    float u = f * (1.0f - lo) + lo;
    u = fmaxf(lo, u);
    return 1.4142135623730951f * erfinvf(u);
}

// z[(b*8+h)*129+n][d] = kmat[..] + exp(0.5*qmat[..]) * eps   (bf16 out)
__global__ __launch_bounds__(256) void z_kernel(
    const float* __restrict__ qmat, const float* __restrict__ kmat, u16* __restrict__ z)
{
    const unsigned int i = blockIdx.x * 256u + threadIdx.x;   // < 16,908,288
    const int d = i & 255; const unsigned int t = i >> 8;
    const int n = t % 129; const int bh = t / 129;
    const int b = bh >> 3, h = bh & 7;
    const long src = ((long)(b * 129 + n)) * 2048 + h * 256 + d;
    const float eps = threefry_normal(i);
    const float zv = kmat[src] + expf(0.5f * qmat[src]) * eps;
    z[i] = f2b(zv);
}

// per-row softmax over 129 cols of dots[66048][144] -> attn bf16, pads zeroed
__global__ __launch_bounds__(256) void softmax_kernel(
    const float* __restrict__ dots, u16* __restrict__ attn)
{
    const int row = blockIdx.x * 4 + (threadIdx.x >> 6);
    const int lane = threadIdx.x & 63;
    const float* dr = dots + (long)row * 144;
    const float v0 = dr[lane];
    const float v1 = dr[64 + lane];
    const float v2 = (lane == 0) ? dr[128] : -1e30f;
    float m = fmaxf(fmaxf(v0, v1), v2);
    #pragma unroll
    for (int o = 32; o > 0; o >>= 1) m = fmaxf(m, __shfl_xor(m, o, 64));
    const float e0 = expf(v0 - m), e1 = expf(v1 - m);
    const float e2 = (lane == 0) ? expf(v2 - m) : 0.0f;
    float s = e0 + e1 + e2;
    #pragma unroll
    for (int o = 32; o > 0; o >>= 1) s += __shfl_xor(s, o, 64);
    const float inv = 1.0f / s;
    u16* ar = attn + (long)row * 144;
    ar[lane] = f2b(e0 * inv);
    ar[64 + lane] = f2b(e1 * inv);
    if (lane < 16) ar[128 + lane] = (lane == 0) ? f2b(e2 * inv) : (u16)0;
}

// LayerNorm row of proj[8256][2048] -> ln bf16
__global__ __launch_bounds__(256) void ln_kernel(
    const float* __restrict__ proj, const float* __restrict__ gamma,
    const float* __restrict__ beta, u16* __restrict__ ln)
{
    const int row = blockIdx.x;
    const float* p = proj + (long)row * 2048;
    const int tid = threadIdx.x;
    float v[8]; float s = 0.f, s2 = 0.f;
    #pragma unroll
    for (int i = 0; i < 8; ++i) {
        v[i] = p[tid + i * 256]; s += v[i]; s2 += v[i] * v[i];
    }
    #pragma unroll
    for (int o = 32; o > 0; o >>= 1) { s += __shfl_down(s, o, 64); s2 += __shfl_down(s2, o, 64); }
    __shared__ float sh[8];
    if ((tid & 63) == 0) { sh[tid >> 6] = s; sh[4 + (tid >> 6)] = s2; }
    __syncthreads();
    s = sh[0] + sh[1] + sh[2] + sh[3];
    s2 = sh[4] + sh[5] + sh[6] + sh[7];
    const float mu = s * (1.0f / 2048.0f);
    const float var = s2 * (1.0f / 2048.0f) - mu * mu;
    const float rinv = 1.0f / sqrtf(var + 1e-5f);
    u16* lr = ln + (long)row * 2048;
    #pragma unroll
    for (int i = 0; i < 8; ++i) {
        const int c = tid + i * 256;
        lr[c] = f2b((v[i] - mu) * rinv * gamma[c] + beta[c]);
    }
}

// per-b L2 norms of q (blocks 0..63) and k (blocks 64..127)
__global__ __launch_bounds__(256) void norm_reduce(
    const float* __restrict__ qmat, const float* __restrict__ kmat, float* __restrict__ norms)
{
    const int b = blockIdx.x & 63;
    const float* src = (blockIdx.x >= 64 ? kmat : qmat) + (long)b * 264192;
    float s = 0.f;
    for (int i = threadIdx.x; i < 264192; i += 256) { const float x = src[i]; s += x * x; }
    #pragma unroll
    for (int o = 32; o > 0; o >>= 1) s += __shfl_down(s, o, 64);
    __shared__ float sh[4];
    if ((threadIdx.x & 63) == 0) sh[threadIdx.x >> 6] = s;
    __syncthreads();
    if (threadIdx.x == 0) norms[blockIdx.x] = sqrtf(sh[0] + sh[1] + sh[2] + sh[3]);
}

// qn/kn: out[b][h][n][d] = mat[(b*129+n)*2048 + h*256+d] / norm[b]
__global__ __launch_bounds__(256) void qn_scatter(
    const float* __restrict__ qmat, const float* __restrict__ kmat,
    const float* __restrict__ norms, float* __restrict__ outq, float* __restrict__ outk)
{
    const unsigned int i = blockIdx.x * 256u + threadIdx.x;
    const int d = i & 255; const unsigned int t = i >> 8;
    const int n = t % 129; const int bh = t / 129;
    const int b = bh >> 3, h = bh & 7;
    const long src = ((long)(b * 129 + n)) * 2048 + h * 256 + d;
    outq[i] = qmat[src] / norms[b];
    outk[i] = kmat[src] / norms[64 + b];
}

// ---------------------------------------------------------------------------
extern "C" void kernel_launch(void* const* d_in, const int* in_sizes, int n_in,
                              void* d_out, int out_size, void* d_ws, size_t ws_size,
                              hipStream_t stream)
{
    const float* x_q   = (const float*)d_in[0];
    const float* x_kv  = (const float*)d_in[1];
    const float* W_ex  = (const float*)d_in[2];
    const float* b_ex  = (const float*)d_in[3];
    const float* W_en  = (const float*)d_in[4];
    const float* b_en  = (const float*)d_in[5];
    const float* pos   = (const float*)d_in[6];
    const float* Wq    = (const float*)d_in[7];
    const float* Wk    = (const float*)d_in[8];
    const float* Wv    = (const float*)d_in[9];
    const float* Wo    = (const float*)d_in[10];
    const float* bo    = (const float*)d_in[11];
    const float* gamma = (const float*)d_in[12];
    const float* beta  = (const float*)d_in[13];
    const float* Wh    = (const float*)d_in[14];
    const float* bh    = (const float*)d_in[15];
    const float* Wm    = (const float*)d_in[16];
    const float* bm    = (const float*)d_in[17];
    (void)in_sizes; (void)n_in; (void)out_size; (void)ws_size;

    // ---- aliased workspace arena (peak ≈ 229.5 MiB) ----
    char* ws = (char*)d_ws;
    char* SA = ws;                      // 67,633,152 B
    char* SB = ws + 67633152UL;         // 67,633,152 B
    char* SC = ws + 135266304UL;        // 37,748,736 B
    char* SD = ws + 173015040UL;        // 33,816,576 B
    char* SE = ws + 206831616UL;        // 33,816,576 B
    char* SF = ws + 240648192UL;        // 512 B

    u16*   Xq_p  = (u16*)SA;
    u16*   Wen_t = (u16*)SA;
    float* qmat  = (float*)SA;
    float* dots  = (float*)SA;
    u16*   outm  = (u16*)SA;
    u16*   ln    = (u16*)SA;

    u16*   Wex_t = (u16*)SB;
    u16*   Xk_p  = (u16*)SB;
    float* kmat  = (float*)SB;
    u16*   attn  = (u16*)SB;
    float* proj  = (float*)SB;

    u16*   Tq    = (u16*)SC;
    u16*   Wv_t  = (u16*)SC;
    u16*   v_t   = (u16*)SC;
    u16*   Wh_t  = (u16*)SC;

    u16*   Tk    = (u16*)SD;
    u16*   z     = (u16*)SD;
    u16*   Wo_t  = (u16*)SD;

    u16*   Wq_t  = (u16*)SE;
    u16*   Wk_t  = (u16*)SE;
    u16*   vmat  = (u16*)SE;
    u16*   Wm_t  = (u16*)SE;

    float* norms = (float*)SF;

    auto launch_gemm = [&](const u16* A, const u16* Bt, void* C, const float* bias,
                           int M, int N, int K, int lda, int ldb, int ldc,
                           float alpha, int cbf16, int remap, int batch,
                           long sA, long sB, long sCo, long sCi, int binner) {
        dim3 grid((M + 127) / 128, (N + 127) / 128, batch);
        gemm_bt<<<grid, 256, 0, stream>>>(A, Bt, C, bias, M, N, K, lda, ldb, ldc,
                                          alpha, cbf16, remap, sA, sB, sCo, sCi, binner);
    };
    auto tconv = [&](const float* in, u16* out, int K, int N, int KP, int NPd) {
        dim3 grid((KP + 31) / 32, (NPd + 31) / 32);
        transpose_conv<<<grid, dim3(32, 8), 0, stream>>>(in, out, K, N, KP, NPd);
    };

    // s1: W_ex^T
    tconv(W_ex, Wex_t, 6272, 2048, 6272, 2048);
    // s2: patchify x_q
    patchify_kernel<<<dim3(25, 4096), 256, 0, stream>>>(x_q, Xq_p);
    // s3: pos tokens into Tq/Tk rows 0..64
    posfill_kernel<<<dim3(8, 65, 64), 256, 0, stream>>>(pos, Tq, Tk);
    // s4: embed q -> Tq rows 65..128 (remapped)
    launch_gemm(Xq_p, Wex_t, Tq, b_ex, 4096, 2048, 6272, 6272, 6272, 2048,
                1.0f, 1, 1, 1, 0, 0, 0, 0, 1);
    // s5: W_en^T (reuses Xq_p slot) + patchify x_kv (reuses Wex_t slot)
    tconv(W_en, Wen_t, 6272, 2048, 6272, 2048);
    patchify_kernel<<<dim3(25, 4096), 256, 0, stream>>>(x_kv, Xk_p);
    // s6: embed kv -> Tk
    launch_gemm(Xk_p, Wen_t, Tk, b_en, 4096, 2048, 6272, 6272, 6272, 2048,
                1.0f, 1, 1, 1, 0, 0, 0, 0, 1);
    // s7: Wq^T, Q GEMM -> qmat f32
    tconv(Wq, Wq_t, 2048, 2048, 2048, 2048);
    launch_gemm(Tq, Wq_t, qmat, nullptr, 8256, 2048, 2048, 2048, 2048, 2048,
                1.0f, 0, 0, 1, 0, 0, 0, 0, 1);
    // s8: Wk^T, K GEMM -> kmat f32
    tconv(Wk, Wk_t, 2048, 2048, 2048, 2048);
    launch_gemm(Tk, Wk_t, kmat, nullptr, 8256, 2048, 2048, 2048, 2048, 2048,
                1.0f, 0, 0, 1, 0, 0, 0, 0, 1);
    // s9: Wv^T, V GEMM -> vmat bf16
    tconv(Wv, Wv_t, 2048, 2048, 2048, 2048);
    launch_gemm(Tk, Wv_t, vmat, nullptr, 8256, 2048, 2048, 2048, 2048, 2048,
                1.0f, 1, 0, 1, 0, 0, 0, 0, 1);
    // s10: v transpose -> v_t [bh][d][n pad144], pads zeroed
    vtrans_kernel<<<dim3(8, 5, 512), dim3(32, 8), 0, stream>>>(vmat, v_t);
    // s11: reparameterize -> z bf16
    z_kernel<<<66048, 256, 0, stream>>>(qmat, kmat, z);
    // s12: qn/kn outputs (head = 8256*6272 = 51,781,632 f32)
    norm_reduce<<<128, 256, 0, stream>>>(qmat, kmat, norms);
    {
        float* outq = (float*)d_out + 51781632L;
        float* outk = outq + 16908288L;
        qn_scatter<<<66048, 256, 0, stream>>>(qmat, kmat, norms, outq, outk);
    }
    // s13: Wm^T (pad rows zeroed), dots GEMM -> dots f32 (reuses qmat slot)
    tconv(Wm, Wm_t, 256, 129, 256, 144);
    launch_gemm(z, Wm_t, dots, bm, 66048, 129, 256, 256, 256, 144,
                0.0625f, 0, 0, 1, 0, 0, 0, 0, 1);
    // s14: softmax -> attn bf16 (reuses kmat slot)
    softmax_kernel<<<16512, 256, 0, stream>>>(dots, attn);
    // s15: attn @ v (batched bh=512) -> outm bf16 (reuses dots slot)
    launch_gemm(attn, v_t, outm, nullptr, 129, 256, 144, 144, 144, 2048,
                1.0f, 1, 0, 512, 129L * 144, 256L * 144, 129L * 2048, 256L, 8);
    // s16: Wo^T, proj GEMM -> proj f32 (reuses attn slot)
    tconv(Wo, Wo_t, 2048, 2048, 2048, 2048);
    launch_gemm(outm, Wo_t, proj, bo, 8256, 2048, 2048, 2048, 2048, 2048,
                1.0f, 0, 0, 1, 0, 0, 0, 0, 1);
    // s17: LayerNorm -> ln bf16 (reuses outm slot)
    ln_kernel<<<8256, 256, 0, stream>>>(proj, gamma, beta, ln);
    // s18: Wh^T, head GEMM -> d_out[0 : 51,781,632] f32
    tconv(Wh, Wh_t, 2048, 6272, 2048, 6272);
    launch_gemm(ln, Wh_t, (float*)d_out, bh, 8256, 6272, 2048, 2048, 2048, 6272,
                1.0f, 0, 0, 1, 0, 0, 0, 0, 1);
}

// Round 4
// 2154.584 us; speedup vs baseline: 1.4048x; 1.4048x over previous
//
#include <hip/hip_runtime.h>

// ---------------------------------------------------------------------------
// CrossAttention_83528523972835 — round 4: performance.
//  * gemm_fast: m97-style global_load_lds(16B) staging, linear LDS [128][64],
//    XCD-bijective block swizzle (m204), for the 7 big GEMMs.
//  * patchify: LDS-staged, coalesced reads/writes (was ~270us each, uncoalesced).
//  * gemm_bt generic kept for dots (N=129) and attn@v (batched, K=144).
// ---------------------------------------------------------------------------

typedef unsigned short u16;
typedef short bf16x8 __attribute__((ext_vector_type(8)));
typedef unsigned short u16x8 __attribute__((ext_vector_type(8)));
typedef float f32x4 __attribute__((ext_vector_type(4)));

static __device__ __forceinline__ u16 f2b(float f) {
    union { float f; unsigned int u; } cv; cv.f = f;
    unsigned int u = cv.u;
    unsigned int lsb = (u >> 16) & 1u;
    u += 0x7fffu + lsb;
    return (u16)(u >> 16);
}

// ---------------------------------------------------------------------------
// Fast bf16 GEMM: C[M,N] = alpha * A[M,K] @ Bt[N,K]^T + bias
// Requirements: N % 128 == 0, K % 64 == 0, rows 16B-aligned (lda/ldb even*8).
// M-edge: load rows clamped to M-1 (valid dup), stores predicated.
// ---------------------------------------------------------------------------
__global__ __launch_bounds__(256) void gemm_fast(
    const u16* __restrict__ A, const u16* __restrict__ Bt, void* __restrict__ Cv,
    const float* __restrict__ bias, int M, int N, int K,
    int lda, int ldb, int ldc, float alpha, int c_bf16, int row_remap)
{
    __shared__ u16 As[128 * 64];
    __shared__ u16 Bs[128 * 64];

    // XCD-aware bijective swizzle (m204): contiguous wgid chunk per XCD
    const int nbx = gridDim.x;
    const int nwg = nbx * gridDim.y;
    const int orig = blockIdx.y * nbx + blockIdx.x;
    const int q = nwg >> 3, r = nwg & 7;
    const int xcd = orig & 7, idx = orig >> 3;
    const int wgid = (xcd < r ? xcd * (q + 1) : r * (q + 1) + (xcd - r) * q) + idx;
    const int bx = wgid % nbx, by = wgid / nbx;

    const int m0 = bx * 128, n0 = by * 128;
    const int tid = threadIdx.x;
    const int lane = tid & 63;
    const int wave = tid >> 6;
    const int wr = wave >> 1, wc = wave & 1;     // 2x2 waves, 64x64 quadrants
    const int l15 = lane & 15, l4 = lane >> 4;

    // staging: 16 segments of 1KB per tile; wave w owns segs w*4..w*4+3.
    // lane l covers seg bytes [l*16, l*16+16) -> row seg*8 + l/8, k (l%8)*8.
    const int lrow = lane >> 3;
    const int lcol = (lane & 7) * 8;

    f32x4 acc[4][4] = {};

    for (int k0 = 0; k0 < K; k0 += 64) {
        __syncthreads();   // WAR: previous tile's reads complete
        #pragma unroll
        for (int j = 0; j < 4; ++j) {
            const int seg = wave * 4 + j;
            const int row = seg * 8 + lrow;
            int ga = m0 + row; ga = ga < M ? ga : M - 1;
            const u16* srcA = A + (long)ga * lda + k0 + lcol;
            __builtin_amdgcn_global_load_lds(
                (const __attribute__((address_space(1))) void*)srcA,
                (__attribute__((address_space(3))) void*)&As[seg * 512], 16, 0, 0);
            const int gb = n0 + row;               // N % 128 == 0: in bounds
            const u16* srcB = Bt + (long)gb * ldb + k0 + lcol;
            __builtin_amdgcn_global_load_lds(
                (const __attribute__((address_space(1))) void*)srcB,
                (__attribute__((address_space(3))) void*)&Bs[seg * 512], 16, 0, 0);
        }
        __syncthreads();   // vmcnt(0) drained by compiler before barrier
        #pragma unroll
        for (int ks = 0; ks < 2; ++ks) {
            bf16x8 af[4], bfr[4];
            #pragma unroll
            for (int m = 0; m < 4; ++m)
                af[m] = *(const bf16x8*)&As[(wr*64 + m*16 + l15) * 64 + ks*32 + l4*8];
            #pragma unroll
            for (int n = 0; n < 4; ++n)
                bfr[n] = *(const bf16x8*)&Bs[(wc*64 + n*16 + l15) * 64 + ks*32 + l4*8];
            #pragma unroll
            for (int m = 0; m < 4; ++m)
                #pragma unroll
                for (int n = 0; n < 4; ++n)
                    acc[m][n] = __builtin_amdgcn_mfma_f32_16x16x32_bf16(
                        af[m], bfr[n], acc[m][n], 0, 0, 0);
        }
    }

    // D mapping: col = lane&15, row = 4*(lane>>4) + reg   [m89-verified]
    #pragma unroll
    for (int m = 0; m < 4; ++m) {
        #pragma unroll
        for (int n = 0; n < 4; ++n) {
            const int col = n0 + wc*64 + n*16 + l15;
            const float bv = bias ? bias[col] : 0.0f;
            #pragma unroll
            for (int j = 0; j < 4; ++j) {
                const int row = m0 + wr*64 + m*16 + l4*4 + j;
                if (row >= M) continue;
                float v = alpha * acc[m][n][j] + bv;
                long crow = row;
                if (row_remap) crow = (long)(row >> 6) * 129 + 65 + (row & 63);
                if (c_bf16) ((u16*)Cv)[crow * (long)ldc + col] = f2b(v);
                else        ((float*)Cv)[crow * (long)ldc + col] = v;
            }
        }
    }
}

// ---------------------------------------------------------------------------
// Generic bf16 GEMM (edges/batch): used for dots (N=129) and attn@v (K=144).
// ---------------------------------------------------------------------------
__global__ __launch_bounds__(256) void gemm_bt(
    const u16* __restrict__ A, const u16* __restrict__ Bt, void* __restrict__ Cv,
    const float* __restrict__ bias, int M, int N, int K,
    int lda, int ldb, int ldc, float alpha, int c_bf16, int row_remap,
    long sA, long sB, long sCo, long sCi, int binner)
{
    const int bz = blockIdx.z;
    const u16* Ab = A + (long)bz * sA;
    const u16* Bb = Bt + (long)bz * sB;
    const long cOff = (long)(bz / binner) * sCo + (long)(bz % binner) * sCi;

    __shared__ u16 As[128][72];
    __shared__ u16 Bs[128][72];

    const int tid = threadIdx.x;
    const int lane = tid & 63;
    const int wave = tid >> 6;
    const int wr = wave >> 1, wc = wave & 1;
    const int l15 = lane & 15, l4 = lane >> 4;
    const int m0 = blockIdx.x * 128, n0 = blockIdx.y * 128;

    const int r = tid >> 3;
    const int kof = (tid & 7) * 8;

    f32x4 acc[4][4] = {};

    const int ktiles = (K + 63) / 64;
    for (int kt = 0; kt < ktiles; ++kt) {
        const int k0 = kt * 64;
        __syncthreads();
        #pragma unroll
        for (int i = 0; i < 4; ++i) {
            const int row = r + 32 * i;
            const int gk = k0 + kof;
            u16x8 v = {0,0,0,0,0,0,0,0};
            const int grow = m0 + row;
            if (grow < M && gk < K)
                v = *(const u16x8*)(Ab + (long)grow * lda + gk);
            *(u16x8*)&As[row][kof] = v;
        }
        #pragma unroll
        for (int i = 0; i < 4; ++i) {
            const int row = r + 32 * i;
            const int gk = k0 + kof;
            u16x8 v = {0,0,0,0,0,0,0,0};
            const int gcol = n0 + row;
            if (gcol < N && gk < K)
                v = *(const u16x8*)(Bb + (long)gcol * ldb + gk);
            *(u16x8*)&Bs[row][kof] = v;
        }
        __syncthreads();
        #pragma unroll
        for (int ks = 0; ks < 2; ++ks) {
            bf16x8 af[4], bfr[4];
            #pragma unroll
            for (int m = 0; m < 4; ++m)
                af[m] = *(const bf16x8*)&As[wr*64 + m*16 + l15][ks*32 + l4*8];
            #pragma unroll
            for (int n = 0; n < 4; ++n)
                bfr[n] = *(const bf16x8*)&Bs[wc*64 + n*16 + l15][ks*32 + l4*8];
            #pragma unroll
            for (int m = 0; m < 4; ++m)
                #pragma unroll
                for (int n = 0; n < 4; ++n)
                    acc[m][n] = __builtin_amdgcn_mfma_f32_16x16x32_bf16(
                        af[m], bfr[n], acc[m][n], 0, 0, 0);
        }
    }

    #pragma unroll
    for (int m = 0; m < 4; ++m) {
        #pragma unroll
        for (int n = 0; n < 4; ++n) {
            const int col = n0 + wc*64 + n*16 + l15;
            if (col >= N) continue;
            const float bv = bias ? bias[col] : 0.0f;
            #pragma unroll
            for (int j = 0; j < 4; ++j) {
                const int row = m0 + wr*64 + m*16 + l4*4 + j;
                if (row >= M) continue;
                float v = alpha * acc[m][n][j] + bv;
                long crow = row;
                if (row_remap) crow = (long)(row >> 6) * 129 + 65 + (row & 63);
                if (c_bf16) ((u16*)Cv)[cOff + crow * (long)ldc + col] = f2b(v);
                else        ((float*)Cv)[cOff + crow * (long)ldc + col] = v;
            }
        }
    }
}

// out[n][k] = (n<N && k<K) ? in[k][n] : 0 ; out is [NPd][KP] bf16
__global__ __launch_bounds__(256) void transpose_conv(
    const float* __restrict__ in, u16* __restrict__ out, int K, int N, int KP, int NPd)
{
    __shared__ float tile[32][33];
    const int k0 = blockIdx.x * 32, n0 = blockIdx.y * 32;
    const int tx = threadIdx.x, ty = threadIdx.y;   // (32,8)
    #pragma unroll
    for (int i = 0; i < 4; ++i) {
        const int k = k0 + ty + i*8, n = n0 + tx;
        tile[ty + i*8][tx] = (k < K && n < N) ? in[(long)k * N + n] : 0.0f;
    }
    __syncthreads();
    #pragma unroll
    for (int i = 0; i < 4; ++i) {
        const int n = n0 + ty + i*8, k = k0 + tx;
        if (n < NPd && k < KP) out[(long)n * KP + k] = f2b(tile[tx][ty + i*8]);
    }
}

// patchify, LDS-staged: block = (cg of 64 ch, hh, b). Coalesced both sides.
// out[b*64 + hh*8+ww][(p1*7+p2)*128 + c] = x[b][c][hh*7+p1][ww*7+p2]
__global__ __launch_bounds__(256) void patchify_kernel(
    const float* __restrict__ x, u16* __restrict__ out)
{
    __shared__ u16 tile[64 * 7 * 58];          // 51,968 B, pad 58 kills conflicts
    const int b = blockIdx.z, hh = blockIdx.y, cg = blockIdx.x;
    const int c0 = cg * 64;
    for (int i = threadIdx.x; i < 64 * 392; i += 256) {
        const int c = i / 392, rem = i - c * 392;
        const int p1 = rem / 56, w = rem - p1 * 56;
        const float v = x[(((long)b * 128 + c0 + c) * 56 + hh * 7 + p1) * 56 + w];
        tile[(c * 7 + p1) * 58 + w] = f2b(v);
    }
    __syncthreads();
    #pragma unroll
    for (int ww = 0; ww < 8; ++ww) {
        const long base = ((long)(b * 64 + hh * 8 + ww)) * 6272 + c0;
        for (int j = threadIdx.x; j < 49 * 64; j += 256) {
            const int c = j & 63, pp = j >> 6;
            const int p1 = pp / 7, p2 = pp - p1 * 7;
            out[base + pp * 128 + c] = tile[(c * 7 + p1) * 58 + ww * 7 + p2];
        }
    }
}

__global__ __launch_bounds__(256) void posfill_kernel(
    const float* __restrict__ pos, u16* __restrict__ Tq, u16* __restrict__ Tk)
{
    const int col = blockIdx.x * 256 + threadIdx.x;
    const int t = blockIdx.y, b = blockIdx.z;
    const u16 v = f2b(pos[(long)t * 2048 + col]);
    const long idx = ((long)b * 129 + t) * 2048 + col;
    Tq[idx] = v; Tk[idx] = v;
}

// v_t[bh][d][n (pad 144)] = vmat[(b*129+n)*2048 + h*256 + d]; pads zeroed
__global__ void vtrans_kernel(const u16* __restrict__ vmat, u16* __restrict__ v_t)
{
    const int bh = blockIdx.z; const int b = bh >> 3, h = bh & 7;
    const int d0 = blockIdx.x * 32, n0 = blockIdx.y * 32;
    __shared__ u16 tile[32][33];
    const int tx = threadIdx.x, ty = threadIdx.y;   // (32,8)
    #pragma unroll
    for (int i = 0; i < 4; ++i) {
        const int n = n0 + ty + i*8;
        if (n < 129)
            tile[ty + i*8][tx] = vmat[((long)b*129 + n) * 2048 + h*256 + d0 + tx];
    }
    __syncthreads();
    #pragma unroll
    for (int i = 0; i < 4; ++i) {
        const int d = d0 + ty + i*8, n = n0 + tx;
        if (n < 144)
            v_t[((long)bh * 256 + d) * 144 + n] = (n < 129) ? tile[tx][ty + i*8] : (u16)0;
    }
}

// --------------------- threefry2x32, partitionable path --------------------
static __device__ __forceinline__ unsigned int rotl32(unsigned int x, int d) {
    return (x << d) | (x >> (32 - d));
}

static __device__ __forceinline__ float threefry_normal(unsigned int i) {
    const unsigned int ks0 = 0u, ks1 = 42u;
    const unsigned int ks2 = ks0 ^ ks1 ^ 0x1BD11BDAu;
    unsigned int x0 = 0u + ks0;        // counts_hi = 0
    unsigned int x1 = i + ks1;         // counts_lo = i
#define TF_R(rr) { x0 += x1; x1 = rotl32(x1, rr); x1 ^= x0; }
    TF_R(13) TF_R(15) TF_R(26) TF_R(6)
    x0 += ks1; x1 += ks2 + 1u;
    TF_R(17) TF_R(29) TF_R(16) TF_R(24)
    x0 += ks2; x1 += ks0 + 2u;
    TF_R(13) TF_R(15) TF_R(26) TF_R(6)
    x0 += ks0; x1 += ks1 + 3u;
    TF_R(17) TF_R(29) TF_R(16) TF_R(24)
    x0 += ks1; x1 += ks2 + 4u;
    TF_R(13) TF_R(15) TF_R(26) TF_R(6)
    x0 += ks2; x1 += ks0 + 5u;
#undef TF_R
    const unsigned int bits = x0 ^ x1;            // partitionable 32-bit path
    const unsigned int fb = (bits >> 9) | 0x3f800000u;
    union { unsigned int u; float f; } cv; cv.u = fb;
    const float f = cv.f - 1.0f;                  // [0,1)
    const float lo = -0.99999994f;                // nextafter(-1,0)
    float u = f * (1.0f - lo) + lo;
    u = fmaxf(lo, u);
    return 1.4142135623730951f * erfinvf(u);
}

// z[(b*8+h)*129+n][d] = kmat[..] + exp(0.5*qmat[..]) * eps   (bf16 out)
__global__ __launch_bounds__(256) void z_kernel(
    const float* __restrict__ qmat, const float* __restrict__ kmat, u16* __restrict__ z)
{
    const unsigned int i = blockIdx.x * 256u + threadIdx.x;   // < 16,908,288
    const int d = i & 255; const unsigned int t = i >> 8;
    const int n = t % 129; const int bh = t / 129;
    const int b = bh >> 3, h = bh & 7;
    const long src = ((long)(b * 129 + n)) * 2048 + h * 256 + d;
    const float eps = threefry_normal(i);
    const float zv = kmat[src] + expf(0.5f * qmat[src]) * eps;
    z[i] = f2b(zv);
}

// per-row softmax over 129 cols of dots[66048][144] -> attn bf16, pads zeroed
__global__ __launch_bounds__(256) void softmax_kernel(
    const float* __restrict__ dots, u16* __restrict__ attn)
{
    const int row = blockIdx.x * 4 + (threadIdx.x >> 6);
    const int lane = threadIdx.x & 63;
    const float* dr = dots + (long)row * 144;
    const float v0 = dr[lane];
    const float v1 = dr[64 + lane];
    const float v2 = (lane == 0) ? dr[128] : -1e30f;
    float m = fmaxf(fmaxf(v0, v1), v2);
    #pragma unroll
    for (int o = 32; o > 0; o >>= 1) m = fmaxf(m, __shfl_xor(m, o, 64));
    const float e0 = expf(v0 - m), e1 = expf(v1 - m);
    const float e2 = (lane == 0) ? expf(v2 - m) : 0.0f;
    float s = e0 + e1 + e2;
    #pragma unroll
    for (int o = 32; o > 0; o >>= 1) s += __shfl_xor(s, o, 64);
    const float inv = 1.0f / s;
    u16* ar = attn + (long)row * 144;
    ar[lane] = f2b(e0 * inv);
    ar[64 + lane] = f2b(e1 * inv);
    if (lane < 16) ar[128 + lane] = (lane == 0) ? f2b(e2 * inv) : (u16)0;
}

// LayerNorm row of proj[8256][2048] -> ln bf16
__global__ __launch_bounds__(256) void ln_kernel(
    const float* __restrict__ proj, const float* __restrict__ gamma,
    const float* __restrict__ beta, u16* __restrict__ ln)
{
    const int row = blockIdx.x;
    const float* p = proj + (long)row * 2048;
    const int tid = threadIdx.x;
    float v[8]; float s = 0.f, s2 = 0.f;
    #pragma unroll
    for (int i = 0; i < 8; ++i) {
        v[i] = p[tid + i * 256]; s += v[i]; s2 += v[i] * v[i];
    }
    #pragma unroll
    for (int o = 32; o > 0; o >>= 1) { s += __shfl_down(s, o, 64); s2 += __shfl_down(s2, o, 64); }
    __shared__ float sh[8];
    if ((tid & 63) == 0) { sh[tid >> 6] = s; sh[4 + (tid >> 6)] = s2; }
    __syncthreads();
    s = sh[0] + sh[1] + sh[2] + sh[3];
    s2 = sh[4] + sh[5] + sh[6] + sh[7];
    const float mu = s * (1.0f / 2048.0f);
    const float var = s2 * (1.0f / 2048.0f) - mu * mu;
    const float rinv = 1.0f / sqrtf(var + 1e-5f);
    u16* lr = ln + (long)row * 2048;
    #pragma unroll
    for (int i = 0; i < 8; ++i) {
        const int c = tid + i * 256;
        lr[c] = f2b((v[i] - mu) * rinv * gamma[c] + beta[c]);
    }
}

// per-b L2 norms of q (blocks 0..63) and k (blocks 64..127)
__global__ __launch_bounds__(256) void norm_reduce(
    const float* __restrict__ qmat, const float* __restrict__ kmat, float* __restrict__ norms)
{
    const int b = blockIdx.x & 63;
    const float* src = (blockIdx.x >= 64 ? kmat : qmat) + (long)b * 264192;
    float s = 0.f;
    for (int i = threadIdx.x; i < 264192; i += 256) { const float x = src[i]; s += x * x; }
    #pragma unroll
    for (int o = 32; o > 0; o >>= 1) s += __shfl_down(s, o, 64);
    __shared__ float sh[4];
    if ((threadIdx.x & 63) == 0) sh[threadIdx.x >> 6] = s;
    __syncthreads();
    if (threadIdx.x == 0) norms[blockIdx.x] = sqrtf(sh[0] + sh[1] + sh[2] + sh[3]);
}

// qn/kn: out[b][h][n][d] = mat[(b*129+n)*2048 + h*256+d] / norm[b]
__global__ __launch_bounds__(256) void qn_scatter(
    const float* __restrict__ qmat, const float* __restrict__ kmat,
    const float* __restrict__ norms, float* __restrict__ outq, float* __restrict__ outk)
{
    const unsigned int i = blockIdx.x * 256u + threadIdx.x;
    const int d = i & 255; const unsigned int t = i >> 8;
    const int n = t % 129; const int bh = t / 129;
    const int b = bh >> 3, h = bh & 7;
    const long src = ((long)(b * 129 + n)) * 2048 + h * 256 + d;
    outq[i] = qmat[src] / norms[b];
    outk[i] = kmat[src] / norms[64 + b];
}

// ---------------------------------------------------------------------------
extern "C" void kernel_launch(void* const* d_in, const int* in_sizes, int n_in,
                              void* d_out, int out_size, void* d_ws, size_t ws_size,
                              hipStream_t stream)
{
    const float* x_q   = (const float*)d_in[0];
    const float* x_kv  = (const float*)d_in[1];
    const float* W_ex  = (const float*)d_in[2];
    const float* b_ex  = (const float*)d_in[3];
    const float* W_en  = (const float*)d_in[4];
    const float* b_en  = (const float*)d_in[5];
    const float* pos   = (const float*)d_in[6];
    const float* Wq    = (const float*)d_in[7];
    const float* Wk    = (const float*)d_in[8];
    const float* Wv    = (const float*)d_in[9];
    const float* Wo    = (const float*)d_in[10];
    const float* bo    = (const float*)d_in[11];
    const float* gamma = (const float*)d_in[12];
    const float* beta  = (const float*)d_in[13];
    const float* Wh    = (const float*)d_in[14];
    const float* bh    = (const float*)d_in[15];
    const float* Wm    = (const float*)d_in[16];
    const float* bm    = (const float*)d_in[17];
    (void)in_sizes; (void)n_in; (void)out_size; (void)ws_size;

    // ---- aliased workspace arena (peak ≈ 229.5 MiB) ----
    char* ws = (char*)d_ws;
    char* SA = ws;                      // 67,633,152 B
    char* SB = ws + 67633152UL;         // 67,633,152 B
    char* SC = ws + 135266304UL;        // 37,748,736 B
    char* SD = ws + 173015040UL;        // 33,816,576 B
    char* SE = ws + 206831616UL;        // 33,816,576 B
    char* SF = ws + 240648192UL;        // 512 B

    u16*   Xq_p  = (u16*)SA;
    u16*   Wen_t = (u16*)SA;
    float* qmat  = (float*)SA;
    float* dots  = (float*)SA;
    u16*   outm  = (u16*)SA;
    u16*   ln    = (u16*)SA;

    u16*   Wex_t = (u16*)SB;
    u16*   Xk_p  = (u16*)SB;
    float* kmat  = (float*)SB;
    u16*   attn  = (u16*)SB;
    float* proj  = (float*)SB;

    u16*   Tq    = (u16*)SC;
    u16*   Wv_t  = (u16*)SC;
    u16*   v_t   = (u16*)SC;
    u16*   Wh_t  = (u16*)SC;

    u16*   Tk    = (u16*)SD;
    u16*   z     = (u16*)SD;
    u16*   Wo_t  = (u16*)SD;

    u16*   Wq_t  = (u16*)SE;
    u16*   Wk_t  = (u16*)SE;
    u16*   vmat  = (u16*)SE;
    u16*   Wm_t  = (u16*)SE;

    float* norms = (float*)SF;

    auto fast_gemm = [&](const u16* A, const u16* Bt, void* C, const float* bias,
                         int M, int N, int K, int lda, int ldb, int ldc,
                         float alpha, int cbf16, int remap) {
        dim3 grid((M + 127) / 128, N / 128);
        gemm_fast<<<grid, 256, 0, stream>>>(A, Bt, C, bias, M, N, K, lda, ldb, ldc,
                                            alpha, cbf16, remap);
    };
    auto slow_gemm = [&](const u16* A, const u16* Bt, void* C, const float* bias,
                         int M, int N, int K, int lda, int ldb, int ldc,
                         float alpha, int cbf16, int remap, int batch,
                         long sA, long sB, long sCo, long sCi, int binner) {
        dim3 grid((M + 127) / 128, (N + 127) / 128, batch);
        gemm_bt<<<grid, 256, 0, stream>>>(A, Bt, C, bias, M, N, K, lda, ldb, ldc,
                                          alpha, cbf16, remap, sA, sB, sCo, sCi, binner);
    };
    auto tconv = [&](const float* in, u16* out, int K, int N, int KP, int NPd) {
        dim3 grid((KP + 31) / 32, (NPd + 31) / 32);
        transpose_conv<<<grid, dim3(32, 8), 0, stream>>>(in, out, K, N, KP, NPd);
    };

    // s1: W_ex^T
    tconv(W_ex, Wex_t, 6272, 2048, 6272, 2048);
    // s2: patchify x_q
    patchify_kernel<<<dim3(2, 8, 64), 256, 0, stream>>>(x_q, Xq_p);
    // s3: pos tokens into Tq/Tk rows 0..64
    posfill_kernel<<<dim3(8, 65, 64), 256, 0, stream>>>(pos, Tq, Tk);
    // s4: embed q -> Tq rows 65..128 (remapped)
    fast_gemm(Xq_p, Wex_t, Tq, b_ex, 4096, 2048, 6272, 6272, 6272, 2048, 1.0f, 1, 1);
    // s5: W_en^T (reuses Xq_p slot) + patchify x_kv (reuses Wex_t slot)
    tconv(W_en, Wen_t, 6272, 2048, 6272, 2048);
    patchify_kernel<<<dim3(2, 8, 64), 256, 0, stream>>>(x_kv, Xk_p);
    // s6: embed kv -> Tk
    fast_gemm(Xk_p, Wen_t, Tk, b_en, 4096, 2048, 6272, 6272, 6272, 2048, 1.0f, 1, 1);
    // s7: Wq^T, Q GEMM -> qmat f32
    tconv(Wq, Wq_t, 2048, 2048, 2048, 2048);
    fast_gemm(Tq, Wq_t, qmat, nullptr, 8256, 2048, 2048, 2048, 2048, 2048, 1.0f, 0, 0);
    // s8: Wk^T, K GEMM -> kmat f32
    tconv(Wk, Wk_t, 2048, 2048, 2048, 2048);
    fast_gemm(Tk, Wk_t, kmat, nullptr, 8256, 2048, 2048, 2048, 2048, 2048, 1.0f, 0, 0);
    // s9: Wv^T, V GEMM -> vmat bf16
    tconv(Wv, Wv_t, 2048, 2048, 2048, 2048);
    fast_gemm(Tk, Wv_t, vmat, nullptr, 8256, 2048, 2048, 2048, 2048, 2048, 1.0f, 1, 0);
    // s10: v transpose -> v_t [bh][d][n pad144], pads zeroed
    vtrans_kernel<<<dim3(8, 5, 512), dim3(32, 8), 0, stream>>>(vmat, v_t);
    // s11: reparameterize -> z bf16
    z_kernel<<<66048, 256, 0, stream>>>(qmat, kmat, z);
    // s12: qn/kn outputs (head = 8256*6272 = 51,781,632 f32)
    norm_reduce<<<128, 256, 0, stream>>>(qmat, kmat, norms);
    {
        float* outq = (float*)d_out + 51781632L;
        float* outk = outq + 16908288L;
        qn_scatter<<<66048, 256, 0, stream>>>(qmat, kmat, norms, outq, outk);
    }
    // s13: Wm^T (pad rows zeroed), dots GEMM -> dots f32 (reuses qmat slot)
    tconv(Wm, Wm_t, 256, 129, 256, 144);
    slow_gemm(z, Wm_t, dots, bm, 66048, 129, 256, 256, 256, 144,
              0.0625f, 0, 0, 1, 0, 0, 0, 0, 1);
    // s14: softmax -> attn bf16 (reuses kmat slot)
    softmax_kernel<<<16512, 256, 0, stream>>>(dots, attn);
    // s15: attn @ v (batched bh=512) -> outm bf16 (reuses dots slot)
    slow_gemm(attn, v_t, outm, nullptr, 129, 256, 144, 144, 144, 2048,
              1.0f, 1, 0, 512, 129L * 144, 256L * 144, 129L * 2048, 256L, 8);
    // s16: Wo^T, proj GEMM -> proj f32 (reuses attn slot)
    tconv(Wo, Wo_t, 2048, 2048, 2048, 2048);
    fast_gemm(outm, Wo_t, proj, bo, 8256, 2048, 2048, 2048, 2048, 2048, 1.0f, 0, 0);
    // s17: LayerNorm -> ln bf16 (reuses outm slot)
    ln_kernel<<<8256, 256, 0, stream>>>(proj, gamma, beta, ln);
    // s18: Wh^T, head GEMM -> d_out[0 : 51,781,632] f32
    tconv(Wh, Wh_t, 2048, 6272, 2048, 6272);
    fast_gemm(ln, Wh_t, (float*)d_out, bh, 8256, 6272, 2048, 2048, 2048, 6272, 1.0f, 0, 0);
}

// Round 5
// 1861.510 us; speedup vs baseline: 1.6260x; 1.1574x over previous
//
#include <hip/hip_runtime.h>

// ---------------------------------------------------------------------------
// CrossAttention_83528523972835 — round 5: pipelined double-buffered GEMM.
// gemm_pipe (all 7 big GEMMs): 128x128 tile, BK=64, LDS dbuf 64KB (2 blk/CU),
// stage(t+1) overlapped with compute(t), ONE barrier per K-step (implicit
// vmcnt(0) drains prefetch), T2 XOR-swizzle (linear gload_lds dest +
// inverse-swizzled global source + swizzled ds_read), T5 setprio, T1 XCD
// bijective swizzle. gemm_bt kept for dots (N=129) / attn@v (batched K=144).
// ---------------------------------------------------------------------------

typedef unsigned short u16;
typedef short bf16x8 __attribute__((ext_vector_type(8)));
typedef unsigned short u16x8 __attribute__((ext_vector_type(8)));
typedef float f32x4 __attribute__((ext_vector_type(4)));

static __device__ __forceinline__ u16 f2b(float f) {
    union { float f; unsigned int u; } cv; cv.f = f;
    unsigned int u = cv.u;
    unsigned int lsb = (u >> 16) & 1u;
    u += 0x7fffu + lsb;
    return (u16)(u >> 16);
}

// ---------------------------------------------------------------------------
// Pipelined bf16 GEMM: C[M,N] = alpha * A[M,K] @ Bt[N,K]^T + bias
// Requirements: N>=128 (edge clamped), K % 64 == 0, rows 16B-aligned.
// LDS swizzle: byte col (7 bits) ^= (row&7)<<4 on BOTH write-source and read.
// ---------------------------------------------------------------------------
__global__ __launch_bounds__(256, 2) void gemm_pipe(
    const u16* __restrict__ A, const u16* __restrict__ Bt, void* __restrict__ Cv,
    const float* __restrict__ bias, int M, int N, int K,
    int lda, int ldb, int ldc, float alpha, int c_bf16, int row_remap)
{
    // [buf0: A 16KB | B 16KB][buf1: A 16KB | B 16KB]  (u16 units)
    __shared__ u16 lds[2 * 16384];

    // T1: XCD-aware bijective swizzle (m204)
    const int nbx = gridDim.x, nwg = nbx * gridDim.y;
    const int orig = blockIdx.y * nbx + blockIdx.x;
    const int q8 = nwg >> 3, r8 = nwg & 7;
    const int xcd = orig & 7, sidx = orig >> 3;
    const int wgid = (xcd < r8 ? xcd * (q8 + 1) : r8 * (q8 + 1) + (xcd - r8) * q8) + sidx;
    const int bx = wgid % nbx, by = wgid / nbx;
    const int m0 = bx * 128, n0 = by * 128;

    const int tid = threadIdx.x, lane = tid & 63, wave = tid >> 6;
    const int wm = wave >> 1, wn = wave & 1;     // 2x2 waves, 64x64 quadrants
    const int l15 = lane & 15, l4 = lane >> 4;

    // staging constants: thread t covers row j*32 + t/8, col bytes (t&7)*16,
    // source col pre-swizzled so that linear LDS + swizzled read = identity.
    const int srow = tid >> 3;                                            // 0..31
    const int scol = (((tid & 7) * 16) ^ (((tid >> 3) & 7) << 4)) >> 1;   // elems
    // fragment read col (u16 units), full 7-bit byte col XORed with row&7:
    const int cf0 = (((0 * 64) + l4 * 16) ^ ((l15 & 7) << 4)) >> 1;
    const int cf1 = (((1 * 64) + l4 * 16) ^ ((l15 & 7) << 4)) >> 1;

    f32x4 acc[4][4] = {};
    const int nt = K >> 6;

    auto STAGE = [&](int c, int t) {
        const int k0 = t << 6;
        #pragma unroll
        for (int j = 0; j < 4; ++j) {
            const int r = j * 32 + srow;
            int ga = m0 + r; ga = ga < M ? ga : M - 1;
            const u16* srcA = A + (long)ga * lda + k0 + scol;
            __builtin_amdgcn_global_load_lds(
                (const __attribute__((address_space(1))) void*)srcA,
                (__attribute__((address_space(3))) void*)&lds[c * 16384 + j * 2048 + wave * 512],
                16, 0, 0);
            int gb = n0 + r; gb = gb < N ? gb : N - 1;
            const u16* srcB = Bt + (long)gb * ldb + k0 + scol;
            __builtin_amdgcn_global_load_lds(
                (const __attribute__((address_space(1))) void*)srcB,
                (__attribute__((address_space(3))) void*)&lds[c * 16384 + 8192 + j * 2048 + wave * 512],
                16, 0, 0);
        }
    };

    STAGE(0, 0);
    __syncthreads();                       // vmcnt(0) drain: tile 0 resident
    for (int t = 0; t < nt; ++t) {
        const int c = t & 1;
        if (t + 1 < nt) STAGE(c ^ 1, t + 1);      // prefetch overlaps compute
        const int ab = c * 16384, bb = ab + 8192;
        #pragma unroll
        for (int kk = 0; kk < 2; ++kk) {
            const int cf = kk ? cf1 : cf0;
            bf16x8 af[4], bfr[4];
            #pragma unroll
            for (int m = 0; m < 4; ++m)
                af[m] = *(const bf16x8*)&lds[ab + (wm * 64 + m * 16 + l15) * 64 + cf];
            #pragma unroll
            for (int n = 0; n < 4; ++n)
                bfr[n] = *(const bf16x8*)&lds[bb + (wn * 64 + n * 16 + l15) * 64 + cf];
            __builtin_amdgcn_s_setprio(1);
            #pragma unroll
            for (int m = 0; m < 4; ++m)
                #pragma unroll
                for (int n = 0; n < 4; ++n)
                    acc[m][n] = __builtin_amdgcn_mfma_f32_16x16x32_bf16(
                        af[m], bfr[n], acc[m][n], 0, 0, 0);
            __builtin_amdgcn_s_setprio(0);
        }
        __syncthreads();   // drains prefetch (vmcnt 0) + closes WAR on buf c
    }

    // D mapping: col = lane&15, row = 4*(lane>>4) + reg   [m89-verified]
    #pragma unroll
    for (int m = 0; m < 4; ++m) {
        #pragma unroll
        for (int n = 0; n < 4; ++n) {
            const int col = n0 + wn * 64 + n * 16 + l15;
            if (col >= N) continue;
            const float bv = bias ? bias[col] : 0.0f;
            #pragma unroll
            for (int j = 0; j < 4; ++j) {
                const int row = m0 + wm * 64 + m * 16 + l4 * 4 + j;
                if (row >= M) continue;
                float v = alpha * acc[m][n][j] + bv;
                long crow = row;
                if (row_remap) crow = (long)(row >> 6) * 129 + 65 + (row & 63);
                if (c_bf16) ((u16*)Cv)[crow * (long)ldc + col] = f2b(v);
                else        ((float*)Cv)[crow * (long)ldc + col] = v;
            }
        }
    }
}

// ---------------------------------------------------------------------------
// Generic bf16 GEMM (edges/batch): used for dots (N=129) and attn@v (K=144).
// ---------------------------------------------------------------------------
__global__ __launch_bounds__(256) void gemm_bt(
    const u16* __restrict__ A, const u16* __restrict__ Bt, void* __restrict__ Cv,
    const float* __restrict__ bias, int M, int N, int K,
    int lda, int ldb, int ldc, float alpha, int c_bf16, int row_remap,
    long sA, long sB, long sCo, long sCi, int binner)
{
    const int bz = blockIdx.z;
    const u16* Ab = A + (long)bz * sA;
    const u16* Bb = Bt + (long)bz * sB;
    const long cOff = (long)(bz / binner) * sCo + (long)(bz % binner) * sCi;

    __shared__ u16 As[128][72];
    __shared__ u16 Bs[128][72];

    const int tid = threadIdx.x;
    const int lane = tid & 63;
    const int wave = tid >> 6;
    const int wr = wave >> 1, wc = wave & 1;
    const int l15 = lane & 15, l4 = lane >> 4;
    const int m0 = blockIdx.x * 128, n0 = blockIdx.y * 128;

    const int r = tid >> 3;
    const int kof = (tid & 7) * 8;

    f32x4 acc[4][4] = {};

    const int ktiles = (K + 63) / 64;
    for (int kt = 0; kt < ktiles; ++kt) {
        const int k0 = kt * 64;
        __syncthreads();
        #pragma unroll
        for (int i = 0; i < 4; ++i) {
            const int row = r + 32 * i;
            const int gk = k0 + kof;
            u16x8 v = {0,0,0,0,0,0,0,0};
            const int grow = m0 + row;
            if (grow < M && gk < K)
                v = *(const u16x8*)(Ab + (long)grow * lda + gk);
            *(u16x8*)&As[row][kof] = v;
        }
        #pragma unroll
        for (int i = 0; i < 4; ++i) {
            const int row = r + 32 * i;
            const int gk = k0 + kof;
            u16x8 v = {0,0,0,0,0,0,0,0};
            const int gcol = n0 + row;
            if (gcol < N && gk < K)
                v = *(const u16x8*)(Bb + (long)gcol * ldb + gk);
            *(u16x8*)&Bs[row][kof] = v;
        }
        __syncthreads();
        #pragma unroll
        for (int ks = 0; ks < 2; ++ks) {
            bf16x8 af[4], bfr[4];
            #pragma unroll
            for (int m = 0; m < 4; ++m)
                af[m] = *(const bf16x8*)&As[wr*64 + m*16 + l15][ks*32 + l4*8];
            #pragma unroll
            for (int n = 0; n < 4; ++n)
                bfr[n] = *(const bf16x8*)&Bs[wc*64 + n*16 + l15][ks*32 + l4*8];
            #pragma unroll
            for (int m = 0; m < 4; ++m)
                #pragma unroll
                for (int n = 0; n < 4; ++n)
                    acc[m][n] = __builtin_amdgcn_mfma_f32_16x16x32_bf16(
                        af[m], bfr[n], acc[m][n], 0, 0, 0);
        }
    }

    #pragma unroll
    for (int m = 0; m < 4; ++m) {
        #pragma unroll
        for (int n = 0; n < 4; ++n) {
            const int col = n0 + wc*64 + n*16 + l15;
            if (col >= N) continue;
            const float bv = bias ? bias[col] : 0.0f;
            #pragma unroll
            for (int j = 0; j < 4; ++j) {
                const int row = m0 + wr*64 + m*16 + l4*4 + j;
                if (row >= M) continue;
                float v = alpha * acc[m][n][j] + bv;
                long crow = row;
                if (row_remap) crow = (long)(row >> 6) * 129 + 65 + (row & 63);
                if (c_bf16) ((u16*)Cv)[cOff + crow * (long)ldc + col] = f2b(v);
                else        ((float*)Cv)[cOff + crow * (long)ldc + col] = v;
            }
        }
    }
}

// out[n][k] = (n<N && k<K) ? in[k][n] : 0 ; out is [NPd][KP] bf16
__global__ __launch_bounds__(256) void transpose_conv(
    const float* __restrict__ in, u16* __restrict__ out, int K, int N, int KP, int NPd)
{
    __shared__ float tile[32][33];
    const int k0 = blockIdx.x * 32, n0 = blockIdx.y * 32;
    const int tx = threadIdx.x, ty = threadIdx.y;   // (32,8)
    #pragma unroll
    for (int i = 0; i < 4; ++i) {
        const int k = k0 + ty + i*8, n = n0 + tx;
        tile[ty + i*8][tx] = (k < K && n < N) ? in[(long)k * N + n] : 0.0f;
    }
    __syncthreads();
    #pragma unroll
    for (int i = 0; i < 4; ++i) {
        const int n = n0 + ty + i*8, k = k0 + tx;
        if (n < NPd && k < KP) out[(long)n * KP + k] = f2b(tile[tx][ty + i*8]);
    }
}

// patchify, LDS-staged: block = (cg of 64 ch, hh, b). Coalesced both sides.
__global__ __launch_bounds__(256) void patchify_kernel(
    const float* __restrict__ x, u16* __restrict__ out)
{
    __shared__ u16 tile[64 * 7 * 58];
    const int b = blockIdx.z, hh = blockIdx.y, cg = blockIdx.x;
    const int c0 = cg * 64;
    for (int i = threadIdx.x; i < 64 * 392; i += 256) {
        const int c = i / 392, rem = i - c * 392;
        const int p1 = rem / 56, w = rem - p1 * 56;
        const float v = x[(((long)b * 128 + c0 + c) * 56 + hh * 7 + p1) * 56 + w];
        tile[(c * 7 + p1) * 58 + w] = f2b(v);
    }
    __syncthreads();
    #pragma unroll
    for (int ww = 0; ww < 8; ++ww) {
        const long base = ((long)(b * 64 + hh * 8 + ww)) * 6272 + c0;
        for (int j = threadIdx.x; j < 49 * 64; j += 256) {
            const int c = j & 63, pp = j >> 6;
            const int p1 = pp / 7, p2 = pp - p1 * 7;
            out[base + pp * 128 + c] = tile[(c * 7 + p1) * 58 + ww * 7 + p2];
        }
    }
}

__global__ __launch_bounds__(256) void posfill_kernel(
    const float* __restrict__ pos, u16* __restrict__ Tq, u16* __restrict__ Tk)
{
    const int col = blockIdx.x * 256 + threadIdx.x;
    const int t = blockIdx.y, b = blockIdx.z;
    const u16 v = f2b(pos[(long)t * 2048 + col]);
    const long idx = ((long)b * 129 + t) * 2048 + col;
    Tq[idx] = v; Tk[idx] = v;
}

// v_t[bh][d][n (pad 144)] = vmat[(b*129+n)*2048 + h*256 + d]; pads zeroed
__global__ void vtrans_kernel(const u16* __restrict__ vmat, u16* __restrict__ v_t)
{
    const int bh = blockIdx.z; const int b = bh >> 3, h = bh & 7;
    const int d0 = blockIdx.x * 32, n0 = blockIdx.y * 32;
    __shared__ u16 tile[32][33];
    const int tx = threadIdx.x, ty = threadIdx.y;   // (32,8)
    #pragma unroll
    for (int i = 0; i < 4; ++i) {
        const int n = n0 + ty + i*8;
        if (n < 129)
            tile[ty + i*8][tx] = vmat[((long)b*129 + n) * 2048 + h*256 + d0 + tx];
    }
    __syncthreads();
    #pragma unroll
    for (int i = 0; i < 4; ++i) {
        const int d = d0 + ty + i*8, n = n0 + tx;
        if (n < 144)
            v_t[((long)bh * 256 + d) * 144 + n] = (n < 129) ? tile[tx][ty + i*8] : (u16)0;
    }
}

// --------------------- threefry2x32, partitionable path --------------------
static __device__ __forceinline__ unsigned int rotl32(unsigned int x, int d) {
    return (x << d) | (x >> (32 - d));
}

static __device__ __forceinline__ float threefry_normal(unsigned int i) {
    const unsigned int ks0 = 0u, ks1 = 42u;
    const unsigned int ks2 = ks0 ^ ks1 ^ 0x1BD11BDAu;
    unsigned int x0 = 0u + ks0;        // counts_hi = 0
    unsigned int x1 = i + ks1;         // counts_lo = i
#define TF_R(rr) { x0 += x1; x1 = rotl32(x1, rr); x1 ^= x0; }
    TF_R(13) TF_R(15) TF_R(26) TF_R(6)
    x0 += ks1; x1 += ks2 + 1u;
    TF_R(17) TF_R(29) TF_R(16) TF_R(24)
    x0 += ks2; x1 += ks0 + 2u;
    TF_R(13) TF_R(15) TF_R(26) TF_R(6)
    x0 += ks0; x1 += ks1 + 3u;
    TF_R(17) TF_R(29) TF_R(16) TF_R(24)
    x0 += ks1; x1 += ks2 + 4u;
    TF_R(13) TF_R(15) TF_R(26) TF_R(6)
    x0 += ks2; x1 += ks0 + 5u;
#undef TF_R
    const unsigned int bits = x0 ^ x1;            // partitionable 32-bit path
    const unsigned int fb = (bits >> 9) | 0x3f800000u;
    union { unsigned int u; float f; } cv; cv.u = fb;
    const float f = cv.f - 1.0f;                  // [0,1)
    const float lo = -0.99999994f;                // nextafter(-1,0)
    float u = f * (1.0f - lo) + lo;
    u = fmaxf(lo, u);
    return 1.4142135623730951f * erfinvf(u);
}

// z[(b*8+h)*129+n][d] = kmat[..] + exp(0.5*qmat[..]) * eps   (bf16 out)
__global__ __launch_bounds__(256) void z_kernel(
    const float* __restrict__ qmat, const float* __restrict__ kmat, u16* __restrict__ z)
{
    const unsigned int i = blockIdx.x * 256u + threadIdx.x;   // < 16,908,288
    const int d = i & 255; const unsigned int t = i >> 8;
    const int n = t % 129; const int bh = t / 129;
    const int b = bh >> 3, h = bh & 7;
    const long src = ((long)(b * 129 + n)) * 2048 + h * 256 + d;
    const float eps = threefry_normal(i);
    const float zv = kmat[src] + expf(0.5f * qmat[src]) * eps;
    z[i] = f2b(zv);
}

// per-row softmax over 129 cols of dots[66048][144] -> attn bf16, pads zeroed
__global__ __launch_bounds__(256) void softmax_kernel(
    const float* __restrict__ dots, u16* __restrict__ attn)
{
    const int row = blockIdx.x * 4 + (threadIdx.x >> 6);
    const int lane = threadIdx.x & 63;
    const float* dr = dots + (long)row * 144;
    const float v0 = dr[lane];
    const float v1 = dr[64 + lane];
    const float v2 = (lane == 0) ? dr[128] : -1e30f;
    float m = fmaxf(fmaxf(v0, v1), v2);
    #pragma unroll
    for (int o = 32; o > 0; o >>= 1) m = fmaxf(m, __shfl_xor(m, o, 64));
    const float e0 = expf(v0 - m), e1 = expf(v1 - m);
    const float e2 = (lane == 0) ? expf(v2 - m) : 0.0f;
    float s = e0 + e1 + e2;
    #pragma unroll
    for (int o = 32; o > 0; o >>= 1) s += __shfl_xor(s, o, 64);
    const float inv = 1.0f / s;
    u16* ar = attn + (long)row * 144;
    ar[lane] = f2b(e0 * inv);
    ar[64 + lane] = f2b(e1 * inv);
    if (lane < 16) ar[128 + lane] = (lane == 0) ? f2b(e2 * inv) : (u16)0;
}

// LayerNorm row of proj[8256][2048] -> ln bf16
__global__ __launch_bounds__(256) void ln_kernel(
    const float* __restrict__ proj, const float* __restrict__ gamma,
    const float* __restrict__ beta, u16* __restrict__ ln)
{
    const int row = blockIdx.x;
    const float* p = proj + (long)row * 2048;
    const int tid = threadIdx.x;
    float v[8]; float s = 0.f, s2 = 0.f;
    #pragma unroll
    for (int i = 0; i < 8; ++i) {
        v[i] = p[tid + i * 256]; s += v[i]; s2 += v[i] * v[i];
    }
    #pragma unroll
    for (int o = 32; o > 0; o >>= 1) { s += __shfl_down(s, o, 64); s2 += __shfl_down(s2, o, 64); }
    __shared__ float sh[8];
    if ((tid & 63) == 0) { sh[tid >> 6] = s; sh[4 + (tid >> 6)] = s2; }
    __syncthreads();
    s = sh[0] + sh[1] + sh[2] + sh[3];
    s2 = sh[4] + sh[5] + sh[6] + sh[7];
    const float mu = s * (1.0f / 2048.0f);
    const float var = s2 * (1.0f / 2048.0f) - mu * mu;
    const float rinv = 1.0f / sqrtf(var + 1e-5f);
    u16* lr = ln + (long)row * 2048;
    #pragma unroll
    for (int i = 0; i < 8; ++i) {
        const int c = tid + i * 256;
        lr[c] = f2b((v[i] - mu) * rinv * gamma[c] + beta[c]);
    }
}

// per-b L2 norms of q (blocks 0..63) and k (blocks 64..127)
__global__ __launch_bounds__(256) void norm_reduce(
    const float* __restrict__ qmat, const float* __restrict__ kmat, float* __restrict__ norms)
{
    const int b = blockIdx.x & 63;
    const float* src = (blockIdx.x >= 64 ? kmat : qmat) + (long)b * 264192;
    float s = 0.f;
    for (int i = threadIdx.x; i < 264192; i += 256) { const float x = src[i]; s += x * x; }
    #pragma unroll
    for (int o = 32; o > 0; o >>= 1) s += __shfl_down(s, o, 64);
    __shared__ float sh[4];
    if ((threadIdx.x & 63) == 0) sh[threadIdx.x >> 6] = s;
    __syncthreads();
    if (threadIdx.x == 0) norms[blockIdx.x] = sqrtf(sh[0] + sh[1] + sh[2] + sh[3]);
}

// qn/kn: out[b][h][n][d] = mat[(b*129+n)*2048 + h*256+d] / norm[b]
__global__ __launch_bounds__(256) void qn_scatter(
    const float* __restrict__ qmat, const float* __restrict__ kmat,
    const float* __restrict__ norms, float* __restrict__ outq, float* __restrict__ outk)
{
    const unsigned int i = blockIdx.x * 256u + threadIdx.x;
    const int d = i & 255; const unsigned int t = i >> 8;
    const int n = t % 129; const int bh = t / 129;
    const int b = bh >> 3, h = bh & 7;
    const long src = ((long)(b * 129 + n)) * 2048 + h * 256 + d;
    outq[i] = qmat[src] / norms[b];
    outk[i] = kmat[src] / norms[64 + b];
}

// ---------------------------------------------------------------------------
extern "C" void kernel_launch(void* const* d_in, const int* in_sizes, int n_in,
                              void* d_out, int out_size, void* d_ws, size_t ws_size,
                              hipStream_t stream)
{
    const float* x_q   = (const float*)d_in[0];
    const float* x_kv  = (const float*)d_in[1];
    const float* W_ex  = (const float*)d_in[2];
    const float* b_ex  = (const float*)d_in[3];
    const float* W_en  = (const float*)d_in[4];
    const float* b_en  = (const float*)d_in[5];
    const float* pos   = (const float*)d_in[6];
    const float* Wq    = (const float*)d_in[7];
    const float* Wk    = (const float*)d_in[8];
    const float* Wv    = (const float*)d_in[9];
    const float* Wo    = (const float*)d_in[10];
    const float* bo    = (const float*)d_in[11];
    const float* gamma = (const float*)d_in[12];
    const float* beta  = (const float*)d_in[13];
    const float* Wh    = (const float*)d_in[14];
    const float* bh    = (const float*)d_in[15];
    const float* Wm    = (const float*)d_in[16];
    const float* bm    = (const float*)d_in[17];
    (void)in_sizes; (void)n_in; (void)out_size; (void)ws_size;

    // ---- aliased workspace arena (peak ≈ 229.5 MiB) ----
    char* ws = (char*)d_ws;
    char* SA = ws;                      // 67,633,152 B
    char* SB = ws + 67633152UL;         // 67,633,152 B
    char* SC = ws + 135266304UL;        // 37,748,736 B
    char* SD = ws + 173015040UL;        // 33,816,576 B
    char* SE = ws + 206831616UL;        // 33,816,576 B
    char* SF = ws + 240648192UL;        // 512 B

    u16*   Xq_p  = (u16*)SA;
    u16*   Wen_t = (u16*)SA;
    float* qmat  = (float*)SA;
    float* dots  = (float*)SA;
    u16*   outm  = (u16*)SA;
    u16*   ln    = (u16*)SA;

    u16*   Wex_t = (u16*)SB;
    u16*   Xk_p  = (u16*)SB;
    float* kmat  = (float*)SB;
    u16*   attn  = (u16*)SB;
    float* proj  = (float*)SB;

    u16*   Tq    = (u16*)SC;
    u16*   Wv_t  = (u16*)SC;
    u16*   v_t   = (u16*)SC;
    u16*   Wh_t  = (u16*)SC;

    u16*   Tk    = (u16*)SD;
    u16*   z     = (u16*)SD;
    u16*   Wo_t  = (u16*)SD;

    u16*   Wq_t  = (u16*)SE;
    u16*   Wk_t  = (u16*)SE;
    u16*   vmat  = (u16*)SE;
    u16*   Wm_t  = (u16*)SE;

    float* norms = (float*)SF;

    auto fast_gemm = [&](const u16* A, const u16* Bt, void* C, const float* bias,
                         int M, int N, int K, int lda, int ldb, int ldc,
                         float alpha, int cbf16, int remap) {
        dim3 grid((M + 127) / 128, (N + 127) / 128);
        gemm_pipe<<<grid, 256, 0, stream>>>(A, Bt, C, bias, M, N, K, lda, ldb, ldc,
                                            alpha, cbf16, remap);
    };
    auto slow_gemm = [&](const u16* A, const u16* Bt, void* C, const float* bias,
                         int M, int N, int K, int lda, int ldb, int ldc,
                         float alpha, int cbf16, int remap, int batch,
                         long sA, long sB, long sCo, long sCi, int binner) {
        dim3 grid((M + 127) / 128, (N + 127) / 128, batch);
        gemm_bt<<<grid, 256, 0, stream>>>(A, Bt, C, bias, M, N, K, lda, ldb, ldc,
                                          alpha, cbf16, remap, sA, sB, sCo, sCi, binner);
    };
    auto tconv = [&](const float* in, u16* out, int K, int N, int KP, int NPd) {
        dim3 grid((KP + 31) / 32, (NPd + 31) / 32);
        transpose_conv<<<grid, dim3(32, 8), 0, stream>>>(in, out, K, N, KP, NPd);
    };

    // s1: W_ex^T
    tconv(W_ex, Wex_t, 6272, 2048, 6272, 2048);
    // s2: patchify x_q
    patchify_kernel<<<dim3(2, 8, 64), 256, 0, stream>>>(x_q, Xq_p);
    // s3: pos tokens into Tq/Tk rows 0..64
    posfill_kernel<<<dim3(8, 65, 64), 256, 0, stream>>>(pos, Tq, Tk);
    // s4: embed q -> Tq rows 65..128 (remapped)
    fast_gemm(Xq_p, Wex_t, Tq, b_ex, 4096, 2048, 6272, 6272, 6272, 2048, 1.0f, 1, 1);
    // s5: W_en^T (reuses Xq_p slot) + patchify x_kv (reuses Wex_t slot)
    tconv(W_en, Wen_t, 6272, 2048, 6272, 2048);
    patchify_kernel<<<dim3(2, 8, 64), 256, 0, stream>>>(x_kv, Xk_p);
    // s6: embed kv -> Tk
    fast_gemm(Xk_p, Wen_t, Tk, b_en, 4096, 2048, 6272, 6272, 6272, 2048, 1.0f, 1, 1);
    // s7: Wq^T, Q GEMM -> qmat f32
    tconv(Wq, Wq_t, 2048, 2048, 2048, 2048);
    fast_gemm(Tq, Wq_t, qmat, nullptr, 8256, 2048, 2048, 2048, 2048, 2048, 1.0f, 0, 0);
    // s8: Wk^T, K GEMM -> kmat f32
    tconv(Wk, Wk_t, 2048, 2048, 2048, 2048);
    fast_gemm(Tk, Wk_t, kmat, nullptr, 8256, 2048, 2048, 2048, 2048, 2048, 1.0f, 0, 0);
    // s9: Wv^T, V GEMM -> vmat bf16
    tconv(Wv, Wv_t, 2048, 2048, 2048, 2048);
    fast_gemm(Tk, Wv_t, vmat, nullptr, 8256, 2048, 2048, 2048, 2048, 2048, 1.0f, 1, 0);
    // s10: v transpose -> v_t [bh][d][n pad144], pads zeroed
    vtrans_kernel<<<dim3(8, 5, 512), dim3(32, 8), 0, stream>>>(vmat, v_t);
    // s11: reparameterize -> z bf16
    z_kernel<<<66048, 256, 0, stream>>>(qmat, kmat, z);
    // s12: qn/kn outputs (head = 8256*6272 = 51,781,632 f32)
    norm_reduce<<<128, 256, 0, stream>>>(qmat, kmat, norms);
    {
        float* outq = (float*)d_out + 51781632L;
        float* outk = outq + 16908288L;
        qn_scatter<<<66048, 256, 0, stream>>>(qmat, kmat, norms, outq, outk);
    }
    // s13: Wm^T (pad rows zeroed), dots GEMM -> dots f32 (reuses qmat slot)
    tconv(Wm, Wm_t, 256, 129, 256, 144);
    slow_gemm(z, Wm_t, dots, bm, 66048, 129, 256, 256, 256, 144,
              0.0625f, 0, 0, 1, 0, 0, 0, 0, 1);
    // s14: softmax -> attn bf16 (reuses kmat slot)
    softmax_kernel<<<16512, 256, 0, stream>>>(dots, attn);
    // s15: attn @ v (batched bh=512) -> outm bf16 (reuses dots slot)
    slow_gemm(attn, v_t, outm, nullptr, 129, 256, 144, 144, 144, 2048,
              1.0f, 1, 0, 512, 129L * 144, 256L * 144, 129L * 2048, 256L, 8);
    // s16: Wo^T, proj GEMM -> proj f32 (reuses attn slot)
    tconv(Wo, Wo_t, 2048, 2048, 2048, 2048);
    fast_gemm(outm, Wo_t, proj, bo, 8256, 2048, 2048, 2048, 2048, 2048, 1.0f, 0, 0);
    // s17: LayerNorm -> ln bf16 (reuses outm slot)
    ln_kernel<<<8256, 256, 0, stream>>>(proj, gamma, beta, ln);
    // s18: Wh^T, head GEMM -> d_out[0 : 51,781,632] f32
    tconv(Wh, Wh_t, 2048, 6272, 2048, 6272);
    fast_gemm(ln, Wh_t, (float*)d_out, bh, 8256, 6272, 2048, 2048, 2048, 6272, 1.0f, 0, 0);
}